// Round 8
// baseline (369.371 us; speedup 1.0000x reference)
//
#include <hip/hip_runtime.h>
#include <hip/hip_bf16.h>

#define N_NODES 100000
#define N_EDGES 1600000
#define IN_DIM  128
#define HID_DIM 128
#define OUT_DIM 64
#define SCAN_CHUNK 1024
#define NBLK_SCAN ((N_NODES + SCAN_CHUNK - 1) / SCAN_CHUNK)  // 98
#define DEG_BLOCKS ((N_EDGES + 1023) / 1024)                 // 1563 (4 edges/thread)
#define CAST_BLOCKS ((N_NODES * (IN_DIM / 4) + 255) / 256)   // 12500

typedef _Float16 half2v __attribute__((ext_vector_type(2)));
typedef _Float16 half8  __attribute__((ext_vector_type(8)));
typedef __attribute__((ext_vector_type(4))) float floatx4;

__device__ __forceinline__ float eluf(float x) { return x > 0.0f ? x : expm1f(x); }
__device__ __forceinline__ unsigned packh(float a, float b) {
    union { _Float16 h[2]; unsigned u; } c;
    c.h[0] = (_Float16)a; c.h[1] = (_Float16)b; return c.u;
}
__device__ __forceinline__ half2v as_h2(unsigned u) {
    union { unsigned u; half2v h; } c; c.u = u; return c.h;
}

// ---- edge_index dtype probe: int64 data has all-zero odd int32 words ----
__global__ void k_detect(const int* __restrict__ ei, int* __restrict__ flag) {
    __shared__ int acc;
    if (threadIdx.x == 0) acc = 0;
    __syncthreads();
    int v = 0;
    for (int e = threadIdx.x; e < 1024; e += 256) v |= ei[2 * e + 1];
    atomicOr(&acc, v);
    __syncthreads();
    if (threadIdx.x == 0) flag[0] = (acc == 0) ? 1 : 0;
}
__device__ __forceinline__ int esrc(const int* ei, int e, int is64) {
    return is64 ? ei[2 * e] : ei[e];
}
__device__ __forceinline__ int edst(const int* ei, int e, int is64) {
    return is64 ? ei[2 * (N_EDGES + e)] : ei[N_EDGES + e];
}

// =================== fused: degree/epos atomic pass + x->f16 cast ===================
__global__ void k_prolog(const int* __restrict__ ei, const int* __restrict__ flag,
                         int* __restrict__ deg, unsigned short* __restrict__ epos,
                         const float4* __restrict__ x4, uint2* __restrict__ xh) {
    int b = blockIdx.x;
    if (b < DEG_BLOCKS) {
        int base = (b * 256 + threadIdx.x) * 4;
        int is64 = flag[0];
        unsigned short ep[4];
#pragma unroll
        for (int q = 0; q < 4; q++) {
            int e = base + q;
            if (e < N_EDGES) {
                int d = edst(ei, e, is64);
                ep[q] = (unsigned short)atomicAdd(&deg[d], 1);
            } else ep[q] = 0;
        }
        if (base + 3 < N_EDGES) {
            *(ushort4*)(epos + base) = make_ushort4(ep[0], ep[1], ep[2], ep[3]);
        } else {
#pragma unroll
            for (int q = 0; q < 4; q++) if (base + q < N_EDGES) epos[base + q] = ep[q];
        }
    } else {
        int i = (b - DEG_BLOCKS) * 256 + threadIdx.x;
        if (i >= N_NODES * (IN_DIM / 4)) return;
        float4 v = x4[i];
        uint2 o = { packh(v.x, v.y), packh(v.z, v.w) };
        xh[i] = o;
    }
}

// scan over degrees (also emits dinv = rsqrt(deg+1))
__global__ void k_scan1(const int* __restrict__ deg, int* __restrict__ rowStart,
                        int* __restrict__ bsum, float* __restrict__ dinv) {
    __shared__ int sd[256];
    int t = threadIdx.x, blk = blockIdx.x;
    int i0 = blk * SCAN_CHUNK + t * 4;
    int d0 = (i0 + 0 < N_NODES) ? deg[i0 + 0] : 0;
    int d1 = (i0 + 1 < N_NODES) ? deg[i0 + 1] : 0;
    int d2 = (i0 + 2 < N_NODES) ? deg[i0 + 2] : 0;
    int d3 = (i0 + 3 < N_NODES) ? deg[i0 + 3] : 0;
    if (i0 + 0 < N_NODES) dinv[i0 + 0] = rsqrtf((float)(d0 + 1));
    if (i0 + 1 < N_NODES) dinv[i0 + 1] = rsqrtf((float)(d1 + 1));
    if (i0 + 2 < N_NODES) dinv[i0 + 2] = rsqrtf((float)(d2 + 1));
    if (i0 + 3 < N_NODES) dinv[i0 + 3] = rsqrtf((float)(d3 + 1));
    int s4 = d0 + d1 + d2 + d3;
    sd[t] = s4;
    __syncthreads();
    int acc = s4;
    for (int off = 1; off < 256; off <<= 1) {
        int v = (t >= off) ? sd[t - off] : 0;
        __syncthreads();
        acc += v; sd[t] = acc;
        __syncthreads();
    }
    int excl = acc - s4;
    if (i0 + 0 < N_NODES) rowStart[i0 + 0] = excl;
    if (i0 + 1 < N_NODES) rowStart[i0 + 1] = excl + d0;
    if (i0 + 2 < N_NODES) rowStart[i0 + 2] = excl + d0 + d1;
    if (i0 + 3 < N_NODES) rowStart[i0 + 3] = excl + d0 + d1 + d2;
    if (t == 255) bsum[blk] = acc;
}
// parallel block-sum scan (98 values, one 128-thread block)
__global__ void k_scan2(int* __restrict__ bsum, int* __restrict__ rowStartN) {
    __shared__ int sd[128];
    int t = threadIdx.x;
    int v = (t < NBLK_SCAN) ? bsum[t] : 0;
    sd[t] = v;
    __syncthreads();
    int acc = v;
    for (int off = 1; off < 128; off <<= 1) {
        int u = (t >= off) ? sd[t - off] : 0;
        __syncthreads();
        acc += u; sd[t] = acc;
        __syncthreads();
    }
    if (t < NBLK_SCAN) bsum[t] = acc - v;       // exclusive
    if (t == NBLK_SCAN - 1) rowStartN[0] = acc; // total
}
__global__ void k_scan3(int* __restrict__ rowStart, const int* __restrict__ bsum) {
    int i = blockIdx.x * blockDim.x + threadIdx.x;
    if (i < N_NODES) rowStart[i] += bsum[i >> 10];
}
// atomic-free fill (4 edges/thread): slot was precomputed in k_prolog
__global__ void k_fill(const int* __restrict__ ei, const int* __restrict__ flag,
                       const int* __restrict__ rowStart, const unsigned short* __restrict__ epos,
                       int* __restrict__ csr) {
    int base = (blockIdx.x * 256 + threadIdx.x) * 4;
    int is64 = flag[0];
#pragma unroll
    for (int q = 0; q < 4; q++) {
        int e = base + q;
        if (e < N_EDGES) {
            int s = esrc(ei, e, is64), d = edst(ei, e, is64);
            csr[rowStart[d] + (int)epos[e]] = s;
        }
    }
}

// =================== pull aggregation (f16 rows, fp32 accum, unroll-8) ===================
// one wave per node; lane = u32 (2 f16 cols) of the 128-wide row
__launch_bounds__(256)
__global__ void k_gather1(const unsigned* __restrict__ xh, const float* __restrict__ dinv,
                          const int* __restrict__ row, const int* __restrict__ csr,
                          unsigned* __restrict__ agg) {
    int w = (blockIdx.x * blockDim.x + threadIdx.x) >> 6;
    int lane = threadIdx.x & 63;
    if (w >= N_NODES) return;
    int beg = row[w], end = row[w + 1];
    float dd = dinv[w];
    half2v sv = as_h2(xh[w * 64 + lane]);
    float ax = (float)sv[0] * dd, ay = (float)sv[1] * dd;
    int j = beg;
    for (; j + 8 <= end; j += 8) {
        int s[8]; float wd[8]; unsigned u[8];
#pragma unroll
        for (int q = 0; q < 8; q++) s[q] = csr[j + q];
#pragma unroll
        for (int q = 0; q < 8; q++) wd[q] = dinv[s[q]];
#pragma unroll
        for (int q = 0; q < 8; q++) u[q] = xh[s[q] * 64 + lane];
#pragma unroll
        for (int q = 0; q < 8; q++) {
            half2v h = as_h2(u[q]);
            ax = fmaf((float)h[0], wd[q], ax);
            ay = fmaf((float)h[1], wd[q], ay);
        }
    }
    for (; j < end; j++) {
        int s0 = csr[j]; float w0 = dinv[s0];
        half2v h = as_h2(xh[s0 * 64 + lane]);
        ax = fmaf((float)h[0], w0, ax);
        ay = fmaf((float)h[1], w0, ay);
    }
    agg[w * 64 + lane] = packh(ax * dd, ay * dd);
}

// one HALF-wave per node over h2 (64 f16 cols = 32 u32); fused bias+ELU -> fp32 out
__launch_bounds__(256)
__global__ void k_gather2(const unsigned* __restrict__ h2, const float* __restrict__ dinv,
                          const int* __restrict__ row, const int* __restrict__ csr,
                          const float* __restrict__ b2, float* __restrict__ out) {
    int w = (blockIdx.x * blockDim.x + threadIdx.x) >> 5;
    int p = threadIdx.x & 31;
    if (w >= N_NODES) return;
    float2 bias = *(const float2*)(b2 + 2 * p);
    int beg = row[w], end = row[w + 1];
    float dd = dinv[w];
    half2v sv = as_h2(h2[w * 32 + p]);
    float ax = (float)sv[0] * dd, ay = (float)sv[1] * dd;
    int j = beg;
    for (; j + 8 <= end; j += 8) {
        int s[8]; float wd[8]; unsigned u[8];
#pragma unroll
        for (int q = 0; q < 8; q++) s[q] = csr[j + q];
#pragma unroll
        for (int q = 0; q < 8; q++) wd[q] = dinv[s[q]];
#pragma unroll
        for (int q = 0; q < 8; q++) u[q] = h2[s[q] * 32 + p];
#pragma unroll
        for (int q = 0; q < 8; q++) {
            half2v h = as_h2(u[q]);
            ax = fmaf((float)h[0], wd[q], ax);
            ay = fmaf((float)h[1], wd[q], ay);
        }
    }
    for (; j < end; j++) {
        int s0 = csr[j]; float w0 = dinv[s0];
        half2v h = as_h2(h2[s0 * 32 + p]);
        ax = fmaf((float)h[0], w0, ax);
        ay = fmaf((float)h[1], w0, ay);
    }
    ax *= dd; ay *= dd;
    float2 r = { eluf(ax + bias.x), eluf(ay + bias.y) };
    *(float2*)(out + w * OUT_DIM + 2 * p) = r;
}

// =================== MFMA GEMMs (f16, transposed orientation) ===================
// h1 = elu(aggx @ W1 + b1), IN-PLACE on agg (wave reads its 16 rows fully before storing)
__launch_bounds__(256)
__global__ void k_gemm1_mfma(unsigned* __restrict__ agg, const float* __restrict__ W1,
                             const float* __restrict__ b1, int nblk) {
    __shared__ _Float16 w1p[4][8][64][8];  // [kk][ct][lane][j], 32 KB
    int t = threadIdx.x;
    for (int idx = t; idx < 8192; idx += 256) {  // u32 units
        int j2 = idx & 3, l = (idx >> 2) & 63, ct = (idx >> 8) & 7, kk = idx >> 11;
        int k = kk * 32 + (l >> 4) * 8 + j2 * 2;
        int c = ct * 16 + (l & 15);
        ((unsigned*)w1p)[idx] = packh(W1[k * HID_DIM + c], W1[(k + 1) * HID_DIM + c]);
    }
    int lane = t & 63, wave = t >> 6;
    int q = lane >> 4, m = lane & 15;
    floatx4 bias[8];
#pragma unroll
    for (int ct = 0; ct < 8; ct++) bias[ct] = *(const floatx4*)(b1 + ct * 16 + q * 4);
    __syncthreads();
    for (int blk = blockIdx.x * 4 + wave; blk < nblk; blk += gridDim.x * 4) {
        int r = blk * 16 + m;
        const half8* arow = (const half8*)(agg + r * 64);
        half8 bfr[4];
#pragma unroll
        for (int kk = 0; kk < 4; kk++) bfr[kk] = arow[kk * 4 + q];
        floatx4 acc[8];
#pragma unroll
        for (int ct = 0; ct < 8; ct++) acc[ct] = (floatx4)0.0f;
#pragma unroll
        for (int kk = 0; kk < 4; kk++)
#pragma unroll
            for (int ct = 0; ct < 8; ct++) {
                half8 af = *(const half8*)(&w1p[kk][ct][lane][0]);
                acc[ct] = __builtin_amdgcn_mfma_f32_16x16x32_f16(af, bfr[kk], acc[ct], 0, 0, 0);
            }
        unsigned* hrow = agg + r * 64;
#pragma unroll
        for (int ct = 0; ct < 8; ct++) {
            uint2 o;
            o.x = packh(eluf(acc[ct][0] + bias[ct][0]), eluf(acc[ct][1] + bias[ct][1]));
            o.y = packh(eluf(acc[ct][2] + bias[ct][2]), eluf(acc[ct][3] + bias[ct][3]));
            *(uint2*)(hrow + ct * 8 + q * 2) = o;
        }
    }
}

// h2 = h1 @ W2 (bias/elu deferred to after aggregation), f16 out
__launch_bounds__(256)
__global__ void k_gemm2_mfma(const unsigned* __restrict__ h1, const float* __restrict__ W2,
                             unsigned* __restrict__ h2, int nblk) {
    __shared__ _Float16 w2p[4][4][64][8];  // 16 KB
    int t = threadIdx.x;
    for (int idx = t; idx < 4096; idx += 256) {
        int j2 = idx & 3, l = (idx >> 2) & 63, ct = (idx >> 8) & 3, kk = idx >> 10;
        int k = kk * 32 + (l >> 4) * 8 + j2 * 2;
        int c = ct * 16 + (l & 15);
        ((unsigned*)w2p)[idx] = packh(W2[k * OUT_DIM + c], W2[(k + 1) * OUT_DIM + c]);
    }
    int lane = t & 63, wave = t >> 6;
    int q = lane >> 4, m = lane & 15;
    __syncthreads();
    for (int blk = blockIdx.x * 4 + wave; blk < nblk; blk += gridDim.x * 4) {
        int r = blk * 16 + m;
        const half8* arow = (const half8*)(h1 + r * 64);
        half8 bfr[4];
#pragma unroll
        for (int kk = 0; kk < 4; kk++) bfr[kk] = arow[kk * 4 + q];
        floatx4 acc[4];
#pragma unroll
        for (int ct = 0; ct < 4; ct++) acc[ct] = (floatx4)0.0f;
#pragma unroll
        for (int kk = 0; kk < 4; kk++)
#pragma unroll
            for (int ct = 0; ct < 4; ct++) {
                half8 af = *(const half8*)(&w2p[kk][ct][lane][0]);
                acc[ct] = __builtin_amdgcn_mfma_f32_16x16x32_f16(af, bfr[kk], acc[ct], 0, 0, 0);
            }
        unsigned* orow = h2 + r * 32;
#pragma unroll
        for (int ct = 0; ct < 4; ct++) {
            uint2 o;
            o.x = packh(acc[ct][0], acc[ct][1]);
            o.y = packh(acc[ct][2], acc[ct][3]);
            *(uint2*)(orow + ct * 8 + q * 2) = o;
        }
    }
}

extern "C" void kernel_launch(void* const* d_in, const int* in_sizes, int n_in,
                              void* d_out, int out_size, void* d_ws, size_t ws_size,
                              hipStream_t stream) {
    const float* x  = (const float*)d_in[0];
    const int*   ei = (const int*)d_in[1];
    const float* W1 = (const float*)d_in[2];
    const float* b1 = (const float*)d_in[3];
    const float* W2 = (const float*)d_in[4];
    const float* b2 = (const float*)d_in[5];

    // ---- layout (u32 units) — byte-identical to round 7 ----
    const size_t OFF_FLAG = 0, OFF_DEG = 16, OFF_ROW = 100016, OFF_BSUM = 200032,
                 OFF_CSR = 200192, OFF_DINV = 1800192,
                 OFF_XB = 1900288,          // x f16 [N,128] (6.4M u32); later h2 f16 [N,64]
                 OFF_AGG = 8300288;         // epos(ushort) during CSR build; then aggx f16 -> h1
    const size_t needed = (OFF_AGG + 6400000) * 4;  // 58,801,152 B
    if (ws_size < needed) return;  // canary: zero output, finite absmax

    int*      flag = (int*)d_ws + OFF_FLAG;
    int*      deg  = (int*)d_ws + OFF_DEG;
    int*      row  = (int*)d_ws + OFF_ROW;
    int*      bsum = (int*)d_ws + OFF_BSUM;
    int*      csr  = (int*)d_ws + OFF_CSR;
    float*    dinv = (float*)d_ws + OFF_DINV;
    unsigned* xh   = (unsigned*)d_ws + OFF_XB;
    unsigned* agg  = (unsigned*)d_ws + OFF_AGG;
    unsigned short* epos = (unsigned short*)agg;  // dead slot during CSR build

    // CSR build (single atomic pass, fused with x->f16 cast)
    k_detect<<<1, 256, 0, stream>>>(ei, flag);
    hipMemsetAsync(deg, 0, N_NODES * sizeof(int), stream);
    k_prolog<<<DEG_BLOCKS + CAST_BLOCKS, 256, 0, stream>>>(
        ei, flag, deg, epos, (const float4*)x, (uint2*)xh);
    k_scan1<<<NBLK_SCAN, 256, 0, stream>>>(deg, row, bsum, dinv);
    k_scan2<<<1, 128, 0, stream>>>(bsum, row + N_NODES);
    k_scan3<<<(N_NODES + 255) / 256, 256, 0, stream>>>(row, bsum);
    k_fill<<<(N_EDGES / 4 + 255) / 256, 256, 0, stream>>>(ei, flag, row, epos, csr);

    // layer 1: pull-aggregate xh -> agg (f16), MFMA GEMM in place (+bias+ELU)
    k_gather1<<<(N_NODES * 64 + 255) / 256, 256, 0, stream>>>(xh, dinv, row, csr, agg);
    k_gemm1_mfma<<<1024, 256, 0, stream>>>(agg, W1, b1, N_NODES / 16);

    // layer 2: MFMA GEMM h1 -> h2 (f16, reuses xh slot), pull-aggregate + bias + ELU -> out
    k_gemm2_mfma<<<1024, 256, 0, stream>>>(agg, W2, xh, N_NODES / 16);
    k_gather2<<<(N_NODES * 32 + 255) / 256, 256, 0, stream>>>(
        xh, dinv, row, csr, b2, (float*)d_out);
}

// Round 9
// 358.004 us; speedup vs baseline: 1.0318x; 1.0318x over previous
//
#include <hip/hip_runtime.h>
#include <hip/hip_bf16.h>

#define N_NODES 100000
#define N_EDGES 1600000
#define E_HALF  800000
#define IN_DIM  128
#define HID_DIM 128
#define OUT_DIM 64
#define SCAN_CHUNK 1024
#define NBLK_SCAN ((N_NODES + SCAN_CHUNK - 1) / SCAN_CHUNK)  // 98
#define DEG_BLOCKS ((N_EDGES + 255) / 256)                   // 6250 (1 edge/thread)
#define CAST_BLOCKS ((N_NODES * (IN_DIM / 4) + 255) / 256)   // 12500

typedef __attribute__((ext_vector_type(8))) short short8;
typedef __attribute__((ext_vector_type(4))) float floatx4;

__device__ __forceinline__ float eluf(float x) { return x > 0.0f ? x : expm1f(x); }
__device__ __forceinline__ unsigned short bfbits(float f) {
    union { __hip_bfloat16 h; unsigned short u; } c; c.h = __float2bfloat16(f); return c.u;
}
__device__ __forceinline__ unsigned packbf(float a, float b) {
    return (unsigned)bfbits(a) | ((unsigned)bfbits(b) << 16);
}
__device__ __forceinline__ float lo16(unsigned u) { return __uint_as_float(u << 16); }
__device__ __forceinline__ float hi16(unsigned u) { return __uint_as_float(u & 0xffff0000u); }

// ---- edge_index dtype probe: int64 data has all-zero odd int32 words ----
__global__ void k_detect(const int* __restrict__ ei, int* __restrict__ flag) {
    __shared__ int acc;
    if (threadIdx.x == 0) acc = 0;
    __syncthreads();
    int v = 0;
    for (int e = threadIdx.x; e < 1024; e += 256) v |= ei[2 * e + 1];
    atomicOr(&acc, v);
    __syncthreads();
    if (threadIdx.x == 0) flag[0] = (acc == 0) ? 1 : 0;
}
__device__ __forceinline__ int esrc(const int* ei, int e, int is64) {
    return is64 ? ei[2 * e] : ei[e];
}
__device__ __forceinline__ int edst(const int* ei, int e, int is64) {
    return is64 ? ei[2 * (N_EDGES + e)] : ei[N_EDGES + e];
}

// ======= fused: 2-way-sharded degree/epos atomic pass + x->bf16 cast =======
__global__ void k_prolog(const int* __restrict__ ei, const int* __restrict__ flag,
                         int* __restrict__ degA, int* __restrict__ degB,
                         unsigned short* __restrict__ epos,
                         const float4* __restrict__ x4, uint2* __restrict__ xb) {
    int b = blockIdx.x;
    if (b < DEG_BLOCKS) {
        int e = b * 256 + threadIdx.x;
        if (e >= N_EDGES) return;
        int d = edst(ei, e, flag[0]);
        int* deg = (e < E_HALF) ? degA : degB;
        epos[e] = (unsigned short)atomicAdd(&deg[d], 1);
    } else {
        int i = (b - DEG_BLOCKS) * 256 + threadIdx.x;
        if (i >= N_NODES * (IN_DIM / 4)) return;
        float4 v = x4[i];
        uint2 o = { packbf(v.x, v.y), packbf(v.z, v.w) };
        xb[i] = o;
    }
}

// scan over degrees (sum of shards; also emits dinv = rsqrt(deg+1))
__global__ void k_scan1(const int* __restrict__ degA, const int* __restrict__ degB,
                        int* __restrict__ rowStart, int* __restrict__ bsum,
                        float* __restrict__ dinv) {
    __shared__ int sd[256];
    int t = threadIdx.x, blk = blockIdx.x;
    int i0 = blk * SCAN_CHUNK + t * 4;
    int d0 = (i0 + 0 < N_NODES) ? degA[i0 + 0] + degB[i0 + 0] : 0;
    int d1 = (i0 + 1 < N_NODES) ? degA[i0 + 1] + degB[i0 + 1] : 0;
    int d2 = (i0 + 2 < N_NODES) ? degA[i0 + 2] + degB[i0 + 2] : 0;
    int d3 = (i0 + 3 < N_NODES) ? degA[i0 + 3] + degB[i0 + 3] : 0;
    if (i0 + 0 < N_NODES) dinv[i0 + 0] = rsqrtf((float)(d0 + 1));
    if (i0 + 1 < N_NODES) dinv[i0 + 1] = rsqrtf((float)(d1 + 1));
    if (i0 + 2 < N_NODES) dinv[i0 + 2] = rsqrtf((float)(d2 + 1));
    if (i0 + 3 < N_NODES) dinv[i0 + 3] = rsqrtf((float)(d3 + 1));
    int s4 = d0 + d1 + d2 + d3;
    sd[t] = s4;
    __syncthreads();
    int acc = s4;
    for (int off = 1; off < 256; off <<= 1) {
        int v = (t >= off) ? sd[t - off] : 0;
        __syncthreads();
        acc += v; sd[t] = acc;
        __syncthreads();
    }
    int excl = acc - s4;
    if (i0 + 0 < N_NODES) rowStart[i0 + 0] = excl;
    if (i0 + 1 < N_NODES) rowStart[i0 + 1] = excl + d0;
    if (i0 + 2 < N_NODES) rowStart[i0 + 2] = excl + d0 + d1;
    if (i0 + 3 < N_NODES) rowStart[i0 + 3] = excl + d0 + d1 + d2;
    if (t == 255) bsum[blk] = acc;
}
// parallel block-sum scan (98 values, one 128-thread block)
__global__ void k_scan2(int* __restrict__ bsum, int* __restrict__ rowStartN) {
    __shared__ int sd[128];
    int t = threadIdx.x;
    int v = (t < NBLK_SCAN) ? bsum[t] : 0;
    sd[t] = v;
    __syncthreads();
    int acc = v;
    for (int off = 1; off < 128; off <<= 1) {
        int u = (t >= off) ? sd[t - off] : 0;
        __syncthreads();
        acc += u; sd[t] = acc;
        __syncthreads();
    }
    if (t < NBLK_SCAN) bsum[t] = acc - v;       // exclusive
    if (t == NBLK_SCAN - 1) rowStartN[0] = acc; // total
}
__global__ void k_scan3(int* __restrict__ rowStart, const int* __restrict__ bsum) {
    int i = blockIdx.x * blockDim.x + threadIdx.x;
    if (i < N_NODES) rowStart[i] += bsum[i >> 10];
}
// atomic-free fill: shard-A edges at epos, shard-B offset by degA[d]
__global__ void k_fill(const int* __restrict__ ei, const int* __restrict__ flag,
                       const int* __restrict__ rowStart, const int* __restrict__ degA,
                       const unsigned short* __restrict__ epos, int* __restrict__ csr) {
    int e = blockIdx.x * blockDim.x + threadIdx.x;
    if (e >= N_EDGES) return;
    int is64 = flag[0];
    int s = esrc(ei, e, is64), d = edst(ei, e, is64);
    int slot = (int)epos[e] + ((e < E_HALF) ? 0 : degA[d]);
    csr[rowStart[d] + slot] = s;
}

// =================== pull aggregation (bf16 rows, fp32 accum, unroll-8) ===================
// one wave per node; lane = u32 (2 cols) of the 128-wide bf16 row
__launch_bounds__(256)
__global__ void k_gather1(const unsigned* __restrict__ xb, const float* __restrict__ dinv,
                          const int* __restrict__ row, const int* __restrict__ csr,
                          unsigned* __restrict__ agg) {
    int w = (blockIdx.x * blockDim.x + threadIdx.x) >> 6;
    int lane = threadIdx.x & 63;
    if (w >= N_NODES) return;
    int beg = row[w], end = row[w + 1];
    float dd = dinv[w];
    unsigned sv = xb[w * 64 + lane];
    float ax = lo16(sv) * dd, ay = hi16(sv) * dd;
    int j = beg;
    for (; j + 8 <= end; j += 8) {
        int s[8]; float wd[8]; unsigned u[8];
#pragma unroll
        for (int q = 0; q < 8; q++) s[q] = csr[j + q];
#pragma unroll
        for (int q = 0; q < 8; q++) wd[q] = dinv[s[q]];
#pragma unroll
        for (int q = 0; q < 8; q++) u[q] = xb[s[q] * 64 + lane];
#pragma unroll
        for (int q = 0; q < 8; q++) { ax += lo16(u[q]) * wd[q]; ay += hi16(u[q]) * wd[q]; }
    }
    for (; j + 2 <= end; j += 2) {
        int s0 = csr[j], s1 = csr[j + 1];
        float w0 = dinv[s0], w1 = dinv[s1];
        unsigned u0 = xb[s0 * 64 + lane];
        unsigned u1 = xb[s1 * 64 + lane];
        ax += lo16(u0) * w0 + lo16(u1) * w1;
        ay += hi16(u0) * w0 + hi16(u1) * w1;
    }
    if (j < end) {
        int s0 = csr[j]; float w0 = dinv[s0];
        unsigned u0 = xb[s0 * 64 + lane];
        ax += lo16(u0) * w0; ay += hi16(u0) * w0;
    }
    agg[w * 64 + lane] = packbf(ax * dd, ay * dd);
}

// one HALF-wave per node over h2 (64 bf16 cols = 32 u32); fused bias+ELU -> fp32 out
__launch_bounds__(256)
__global__ void k_gather2(const unsigned* __restrict__ h2, const float* __restrict__ dinv,
                          const int* __restrict__ row, const int* __restrict__ csr,
                          const float* __restrict__ b2, float* __restrict__ out) {
    int w = (blockIdx.x * blockDim.x + threadIdx.x) >> 5;
    int p = threadIdx.x & 31;
    if (w >= N_NODES) return;
    float2 bias = *(const float2*)(b2 + 2 * p);
    int beg = row[w], end = row[w + 1];
    float dd = dinv[w];
    unsigned sv = h2[w * 32 + p];
    float ax = lo16(sv) * dd, ay = hi16(sv) * dd;
    int j = beg;
    for (; j + 8 <= end; j += 8) {
        int s[8]; float wd[8]; unsigned u[8];
#pragma unroll
        for (int q = 0; q < 8; q++) s[q] = csr[j + q];
#pragma unroll
        for (int q = 0; q < 8; q++) wd[q] = dinv[s[q]];
#pragma unroll
        for (int q = 0; q < 8; q++) u[q] = h2[s[q] * 32 + p];
#pragma unroll
        for (int q = 0; q < 8; q++) { ax += lo16(u[q]) * wd[q]; ay += hi16(u[q]) * wd[q]; }
    }
    for (; j + 2 <= end; j += 2) {
        int s0 = csr[j], s1 = csr[j + 1];
        float w0 = dinv[s0], w1 = dinv[s1];
        unsigned u0 = h2[s0 * 32 + p];
        unsigned u1 = h2[s1 * 32 + p];
        ax += lo16(u0) * w0 + lo16(u1) * w1;
        ay += hi16(u0) * w0 + hi16(u1) * w1;
    }
    if (j < end) {
        int s0 = csr[j]; float w0 = dinv[s0];
        unsigned u0 = h2[s0 * 32 + p];
        ax += lo16(u0) * w0; ay += hi16(u0) * w0;
    }
    ax *= dd; ay *= dd;
    float2 r = { eluf(ax + bias.x), eluf(ay + bias.y) };
    *(float2*)(out + w * OUT_DIM + 2 * p) = r;
}

// =================== MFMA GEMMs (bf16, transposed orientation) ===================
// h1 = elu(aggx @ W1 + b1), IN-PLACE on agg (wave reads its 16 rows fully before storing)
__launch_bounds__(256)
__global__ void k_gemm1_mfma(unsigned* __restrict__ agg, const float* __restrict__ W1,
                             const float* __restrict__ b1, int nblk) {
    __shared__ short w1p[4][8][64][8];  // [kk][ct][lane][j], 32 KB
    int t = threadIdx.x;
    for (int idx = t; idx < 8192; idx += 256) {  // u32 units
        int j2 = idx & 3, l = (idx >> 2) & 63, ct = (idx >> 8) & 7, kk = idx >> 11;
        int k = kk * 32 + (l >> 4) * 8 + j2 * 2;
        int c = ct * 16 + (l & 15);
        ((unsigned*)w1p)[idx] = packbf(W1[k * HID_DIM + c], W1[(k + 1) * HID_DIM + c]);
    }
    int lane = t & 63, wave = t >> 6;
    int q = lane >> 4, m = lane & 15;
    floatx4 bias[8];
#pragma unroll
    for (int ct = 0; ct < 8; ct++) bias[ct] = *(const floatx4*)(b1 + ct * 16 + q * 4);
    __syncthreads();
    for (int blk = blockIdx.x * 4 + wave; blk < nblk; blk += gridDim.x * 4) {
        int r = blk * 16 + m;
        const short8* arow = (const short8*)(agg + r * 64);
        short8 bfr[4];
#pragma unroll
        for (int kk = 0; kk < 4; kk++) bfr[kk] = arow[kk * 4 + q];
        floatx4 acc[8];
#pragma unroll
        for (int ct = 0; ct < 8; ct++) acc[ct] = (floatx4)0.0f;
#pragma unroll
        for (int kk = 0; kk < 4; kk++)
#pragma unroll
            for (int ct = 0; ct < 8; ct++) {
                short8 af = *(const short8*)(&w1p[kk][ct][lane][0]);
                acc[ct] = __builtin_amdgcn_mfma_f32_16x16x32_bf16(af, bfr[kk], acc[ct], 0, 0, 0);
            }
        unsigned* hrow = agg + r * 64;
#pragma unroll
        for (int ct = 0; ct < 8; ct++) {
            uint2 o;
            o.x = packbf(eluf(acc[ct][0] + bias[ct][0]), eluf(acc[ct][1] + bias[ct][1]));
            o.y = packbf(eluf(acc[ct][2] + bias[ct][2]), eluf(acc[ct][3] + bias[ct][3]));
            *(uint2*)(hrow + ct * 8 + q * 2) = o;
        }
    }
}

// h2 = h1 @ W2 (bias/elu deferred to after aggregation), bf16 out
__launch_bounds__(256)
__global__ void k_gemm2_mfma(const unsigned* __restrict__ h1, const float* __restrict__ W2,
                             unsigned* __restrict__ h2, int nblk) {
    __shared__ short w2p[4][4][64][8];  // 16 KB
    int t = threadIdx.x;
    for (int idx = t; idx < 4096; idx += 256) {
        int j2 = idx & 3, l = (idx >> 2) & 63, ct = (idx >> 8) & 3, kk = idx >> 10;
        int k = kk * 32 + (l >> 4) * 8 + j2 * 2;
        int c = ct * 16 + (l & 15);
        ((unsigned*)w2p)[idx] = packbf(W2[k * OUT_DIM + c], W2[(k + 1) * OUT_DIM + c]);
    }
    int lane = t & 63, wave = t >> 6;
    int q = lane >> 4, m = lane & 15;
    __syncthreads();
    for (int blk = blockIdx.x * 4 + wave; blk < nblk; blk += gridDim.x * 4) {
        int r = blk * 16 + m;
        const short8* arow = (const short8*)(h1 + r * 64);
        short8 bfr[4];
#pragma unroll
        for (int kk = 0; kk < 4; kk++) bfr[kk] = arow[kk * 4 + q];
        floatx4 acc[4];
#pragma unroll
        for (int ct = 0; ct < 4; ct++) acc[ct] = (floatx4)0.0f;
#pragma unroll
        for (int kk = 0; kk < 4; kk++)
#pragma unroll
            for (int ct = 0; ct < 4; ct++) {
                short8 af = *(const short8*)(&w2p[kk][ct][lane][0]);
                acc[ct] = __builtin_amdgcn_mfma_f32_16x16x32_bf16(af, bfr[kk], acc[ct], 0, 0, 0);
            }
        unsigned* orow = h2 + r * 32;
#pragma unroll
        for (int ct = 0; ct < 4; ct++) {
            uint2 o;
            o.x = packbf(acc[ct][0], acc[ct][1]);
            o.y = packbf(acc[ct][2], acc[ct][3]);
            *(uint2*)(orow + ct * 8 + q * 2) = o;
        }
    }
}

extern "C" void kernel_launch(void* const* d_in, const int* in_sizes, int n_in,
                              void* d_out, int out_size, void* d_ws, size_t ws_size,
                              hipStream_t stream) {
    const float* x  = (const float*)d_in[0];
    const int*   ei = (const int*)d_in[1];
    const float* W1 = (const float*)d_in[2];
    const float* b1 = (const float*)d_in[3];
    const float* W2 = (const float*)d_in[4];
    const float* b2 = (const float*)d_in[5];

    // ---- layout (u32 units) — byte-identical footprint to rounds 5-8 ----
    const size_t OFF_FLAG = 0, OFF_DEG = 16, OFF_ROW = 100016, OFF_BSUM = 200032,
                 OFF_CSR = 200192, OFF_DINV = 1800192,
                 OFF_XB = 1900288,          // x bf16 [N,128] (6.4M u32); later h2 bf16 [N,64]
                 OFF_AGG = 8300288;         // epos+degB during CSR build; then aggx bf16 -> h1
    const size_t needed = (OFF_AGG + 6400000) * 4;  // 58,801,152 B
    if (ws_size < needed) return;  // canary: zero output, finite absmax

    int*      flag = (int*)d_ws + OFF_FLAG;
    int*      degA = (int*)d_ws + OFF_DEG;
    int*      row  = (int*)d_ws + OFF_ROW;
    int*      bsum = (int*)d_ws + OFF_BSUM;
    int*      csr  = (int*)d_ws + OFF_CSR;
    float*    dinv = (float*)d_ws + OFF_DINV;
    unsigned* xb   = (unsigned*)d_ws + OFF_XB;
    unsigned* agg  = (unsigned*)d_ws + OFF_AGG;
    unsigned short* epos = (unsigned short*)agg;     // agg[0 .. 800k) u32
    int*      degB = (int*)agg + 1000000;            // agg[1M .. 1.1M) u32, dead until gather1

    // CSR build (2-way sharded atomic pass, fused with x->bf16 cast)
    k_detect<<<1, 256, 0, stream>>>(ei, flag);
    hipMemsetAsync(degA, 0, N_NODES * sizeof(int), stream);
    hipMemsetAsync(degB, 0, N_NODES * sizeof(int), stream);
    k_prolog<<<DEG_BLOCKS + CAST_BLOCKS, 256, 0, stream>>>(
        ei, flag, degA, degB, epos, (const float4*)x, (uint2*)xb);
    k_scan1<<<NBLK_SCAN, 256, 0, stream>>>(degA, degB, row, bsum, dinv);
    k_scan2<<<1, 128, 0, stream>>>(bsum, row + N_NODES);
    k_scan3<<<(N_NODES + 255) / 256, 256, 0, stream>>>(row, bsum);
    k_fill<<<(N_EDGES + 255) / 256, 256, 0, stream>>>(ei, flag, row, degA, epos, csr);

    // layer 1: pull-aggregate xb -> agg (bf16), MFMA GEMM in place (+bias+ELU)
    k_gather1<<<(N_NODES * 64 + 255) / 256, 256, 0, stream>>>(xb, dinv, row, csr, agg);
    k_gemm1_mfma<<<1024, 256, 0, stream>>>(agg, W1, b1, N_NODES / 16);

    // layer 2: MFMA GEMM h1 -> h2 (bf16, reuses xb slot), pull-aggregate + bias + ELU -> out
    k_gemm2_mfma<<<1024, 256, 0, stream>>>(agg, W2, xb, N_NODES / 16);
    k_gather2<<<(N_NODES * 32 + 255) / 256, 256, 0, stream>>>(
        xb, dinv, row, csr, b2, (float*)d_out);
}